// Round 2
// baseline (899.640 us; speedup 1.0000x reference)
//
#include <hip/hip_runtime.h>
#include <hip/hip_bf16.h>

#define IGNORE_INDEX (-100)

typedef __bf16 bf16_t;
typedef __bf16 bf16x8 __attribute__((ext_vector_type(8)));
typedef float f32x4 __attribute__((ext_vector_type(4)));

constexpr int NTOK = 4096;
constexpr int HID  = 2048;
constexpr int VOC  = 32000;
constexpr int BM = 128, BN = 128, BK = 64;
constexpr int NT_N = VOC / BN;  // 250 n-tiles
constexpr int NT_M = NTOK / BM; // 32 m-tiles

// ---- ws layout (bytes) ----
// Wbf  @ 0          : 32000*2048*2 = 131,072,000
// Xbf  @ 131072000  :  4096*2048*2 =  16,777,216
// pmax @ 147849216  :   250*4096*4 =   4,096,000   ([ntile][row])
// psum @ 151945216  :   250*4096*4 =   4,096,000
// xt   @ 156041216  :      4096*4  =      16,384
// loss @ 156057600  :      4096*4  =      16,384

__device__ __forceinline__ unsigned short f2bf(float f) {
  unsigned int x = __float_as_uint(f);
  return (unsigned short)((x + 0x7fffu + ((x >> 16) & 1u)) >> 16);  // RNE
}

__global__ void cvt_kernel(const float* __restrict__ src, unsigned short* __restrict__ dst, size_t n4) {
  size_t i = (size_t)blockIdx.x * blockDim.x + threadIdx.x;
  size_t stride = (size_t)gridDim.x * blockDim.x;
  const float4* s4 = reinterpret_cast<const float4*>(src);
  ushort4* d4 = reinterpret_cast<ushort4*>(dst);
  for (; i < n4; i += stride) {
    float4 a = s4[i];
    ushort4 o;
    o.x = f2bf(a.x); o.y = f2bf(a.y); o.z = f2bf(a.z); o.w = f2bf(a.w);
    d4[i] = o;
  }
}

// x_t[row] = dot(X[row], W[target[row]]) + bias[target[row]]   (fp32)
__global__ void xt_kernel(const float* __restrict__ X, const float* __restrict__ W,
                          const float* __restrict__ bias, const int* __restrict__ tgt,
                          float* __restrict__ xt) {
  int row = blockIdx.x * 4 + (threadIdx.x >> 6);
  int lane = threadIdx.x & 63;
  if (row >= NTOK) return;
  int t = tgt[row];
  if (t < 0 || t >= VOC) { if (lane == 0) xt[row] = 0.0f; return; }
  const float4* xr = reinterpret_cast<const float4*>(X + (size_t)row * HID);
  const float4* wr = reinterpret_cast<const float4*>(W + (size_t)t * HID);
  float s = 0.0f;
  for (int i = lane; i < HID / 4; i += 64) {
    float4 a = xr[i], b = wr[i];
    s += a.x * b.x + a.y * b.y + a.z * b.z + a.w * b.w;
  }
#pragma unroll
  for (int d = 1; d < 64; d <<= 1) s += __shfl_xor(s, d);
  if (lane == 0) xt[row] = s + bias[t];
}

// Fused bf16 GEMM (logits tile) + per-row (max, sumexp) partials.
// 128x128 tile, BK=64, 4 waves 2x2, global_load_lds width 16,
// XOR-swizzled LDS (chunk ^= row&7) applied on BOTH global-source and ds_read.
__global__ __launch_bounds__(256) void gemm_lse_kernel(
    const bf16_t* __restrict__ Xb, const bf16_t* __restrict__ Wb,
    const float* __restrict__ bias,
    float* __restrict__ pmax, float* __restrict__ psum) {
  __shared__ bf16_t As[BM * BK];   // [128][64] row-major, 16 KB, swizzled chunks
  __shared__ bf16_t Bs[BN * BK];   // [128][64] row-major, 16 KB
  __shared__ float redM[2][BM];
  __shared__ float redS[2][BM];

  // XCD-chunked swizzle + mtile-fastest (8000 % 8 == 0, bijective)
  const int nwg = NT_M * NT_N;
  const int xcd = blockIdx.x & 7;
  const int pos = blockIdx.x >> 3;
  const int wgid = xcd * (nwg / 8) + pos;
  const int mtile = wgid & (NT_M - 1);   // m fastest: 32 consecutive blocks share W panel
  const int ntile = wgid / NT_M;
  const int mbase = mtile * BM;
  const int nbase = ntile * BN;

  const int t = threadIdx.x;
  const int w = t >> 6;
  const int lane = t & 63;
  const int wr = w >> 1, wc = w & 1;   // wave -> 64x64 sub-tile
  const int l15 = lane & 15;
  const int kgrp = lane >> 4;          // 0..3
  const int h = l15 & 7;

  // ---- staging geometry (linear LDS dest, inverse-swizzled global source) ----
  // issue (w,i): LDS bytes [w*4096 + i*1024 + lane*16). row = w*32+i*8+(lane>>3),
  // stored chunk s = lane&7. Want LDS(row, s) = global chunk c = s ^ (row&7),
  // row&7 = lane>>3  =>  c = (lane&7) ^ (lane>>3).
  const int l8 = lane >> 3;
  const int c8 = (lane & 7) ^ l8;
  const int srow = w * 32 + l8;
  const bf16_t* aSt = Xb + (size_t)(mbase + srow) * HID + c8 * 8;
  const bf16_t* bSt = Wb + (size_t)(nbase + srow) * HID + c8 * 8;
  bf16_t* aDst = As + w * 2048;  // elements; +i*512 per issue
  bf16_t* bDst = Bs + w * 2048;

  f32x4 acc[4][4];
#pragma unroll
  for (int mi = 0; mi < 4; ++mi)
#pragma unroll
    for (int ni = 0; ni < 4; ++ni)
#pragma unroll
      for (int j = 0; j < 4; ++j) acc[mi][ni][j] = 0.0f;

  for (int k0 = 0; k0 < HID; k0 += BK) {
    __syncthreads();
#pragma unroll
    for (int i = 0; i < 4; ++i) {
      __builtin_amdgcn_global_load_lds(
          (const __attribute__((address_space(1))) void*)(aSt + k0 + (size_t)i * 8 * HID),
          (__attribute__((address_space(3))) void*)(aDst + i * 512), 16, 0, 0);
      __builtin_amdgcn_global_load_lds(
          (const __attribute__((address_space(1))) void*)(bSt + k0 + (size_t)i * 8 * HID),
          (__attribute__((address_space(3))) void*)(bDst + i * 512), 16, 0, 0);
    }
    __syncthreads();

#pragma unroll
    for (int ks = 0; ks < 2; ++ks) {
      // global chunk c = ks*4 + kgrp, stored at c ^ (row&7), row&7 = l15&7
      const int cofs = ((ks * 4 + kgrp) ^ h) * 8;
      bf16x8 af[4], bfr[4];
#pragma unroll
      for (int mi = 0; mi < 4; ++mi)
        af[mi] = *reinterpret_cast<const bf16x8*>(As + (wr * 64 + mi * 16 + l15) * BK + cofs);
#pragma unroll
      for (int ni = 0; ni < 4; ++ni)
        bfr[ni] = *reinterpret_cast<const bf16x8*>(Bs + (wc * 64 + ni * 16 + l15) * BK + cofs);
#pragma unroll
      for (int mi = 0; mi < 4; ++mi)
#pragma unroll
        for (int ni = 0; ni < 4; ++ni)
          acc[mi][ni] = __builtin_amdgcn_mfma_f32_16x16x32_bf16(af[mi], bfr[ni], acc[mi][ni], 0, 0, 0);
    }
  }

  // epilogue: C frag layout col = lane&15, row = (lane>>4)*4 + j  (m89-verified)
  float bv[4];
#pragma unroll
  for (int ni = 0; ni < 4; ++ni) bv[ni] = bias[nbase + wc * 64 + ni * 16 + l15];

#pragma unroll
  for (int mi = 0; mi < 4; ++mi) {
#pragma unroll
    for (int j = 0; j < 4; ++j) {
      float v0 = acc[mi][0][j] + bv[0];
      float v1 = acc[mi][1][j] + bv[1];
      float v2 = acc[mi][2][j] + bv[2];
      float v3 = acc[mi][3][j] + bv[3];
      float mx = fmaxf(fmaxf(v0, v1), fmaxf(v2, v3));
#pragma unroll
      for (int d = 1; d < 16; d <<= 1) mx = fmaxf(mx, __shfl_xor(mx, d));
      float s = __expf(v0 - mx) + __expf(v1 - mx) + __expf(v2 - mx) + __expf(v3 - mx);
#pragma unroll
      for (int d = 1; d < 16; d <<= 1) s += __shfl_xor(s, d);
      if (l15 == 0) {
        int lr = wr * 64 + mi * 16 + kgrp * 4 + j;
        redM[wc][lr] = mx;
        redS[wc][lr] = s;
      }
    }
  }
  __syncthreads();
  if (t < BM) {
    float m0 = redM[0][t], m1 = redM[1][t];
    float M = fmaxf(m0, m1);
    float S = __expf(m0 - M) * redS[0][t] + __expf(m1 - M) * redS[1][t];
    size_t row = (size_t)mbase + t;
    pmax[(size_t)ntile * NTOK + row] = M;   // coalesced over t
    psum[(size_t)ntile * NTOK + row] = S;
  }
}

// merge 250 partials per row -> lse -> per-row loss
__global__ void lse_kernel(const float* __restrict__ pmax, const float* __restrict__ psum,
                           const float* __restrict__ xt, const int* __restrict__ tgt,
                           float* __restrict__ loss) {
  int row = blockIdx.x * 4 + (threadIdx.x >> 6);
  int lane = threadIdx.x & 63;
  if (row >= NTOK) return;
  float M = -3.4e38f;
  for (int i = lane; i < NT_N; i += 64) M = fmaxf(M, pmax[(size_t)i * NTOK + row]);
#pragma unroll
  for (int d = 1; d < 64; d <<= 1) M = fmaxf(M, __shfl_xor(M, d));
  float S = 0.0f;
  for (int i = lane; i < NT_N; i += 64)
    S += __expf(pmax[(size_t)i * NTOK + row] - M) * psum[(size_t)i * NTOK + row];
#pragma unroll
  for (int d = 1; d < 64; d <<= 1) S += __shfl_xor(S, d);
  if (lane == 0) {
    int tg = tgt[row];
    bool valid = (tg != IGNORE_INDEX);
    float lse = M + __logf(S);
    loss[row] = valid ? (lse - xt[row]) : 0.0f;
  }
}

__global__ void final_kernel(const float* __restrict__ loss, const int* __restrict__ tgt,
                             float* __restrict__ out) {
  __shared__ float shs[256];
  __shared__ float shc[256];
  int tid = threadIdx.x;
  float s = 0.0f, c = 0.0f;
  for (int i = tid; i < NTOK; i += 256) {
    s += loss[i];
    c += (tgt[i] != IGNORE_INDEX) ? 1.0f : 0.0f;
  }
  shs[tid] = s; shc[tid] = c;
  __syncthreads();
  for (int off = 128; off > 0; off >>= 1) {
    if (tid < off) { shs[tid] += shs[tid + off]; shc[tid] += shc[tid + off]; }
    __syncthreads();
  }
  if (tid == 0) out[0] = shs[0] / fmaxf(shc[0], 1.0f);
}

extern "C" void kernel_launch(void* const* d_in, const int* in_sizes, int n_in,
                              void* d_out, int out_size, void* d_ws, size_t ws_size,
                              hipStream_t stream) {
  const float* W    = (const float*)d_in[0];  // [32000][2048]
  const float* X    = (const float*)d_in[1];  // [4096][2048]
  const int*   tgt  = (const int*)d_in[2];    // [4096]
  const float* bias = (const float*)d_in[3];  // [32000]
  float* out = (float*)d_out;

  char* ws = (char*)d_ws;
  bf16_t* Wb   = (bf16_t*)(ws);
  bf16_t* Xb   = (bf16_t*)(ws + 131072000);
  float*  pmax = (float*) (ws + 147849216);
  float*  psum = (float*) (ws + 151945216);
  float*  xt   = (float*) (ws + 156041216);
  float*  loss = (float*) (ws + 156057600);

  cvt_kernel<<<2048, 256, 0, stream>>>(W, (unsigned short*)Wb, (size_t)VOC * HID / 4);
  cvt_kernel<<<512, 256, 0, stream>>>(X, (unsigned short*)Xb, (size_t)NTOK * HID / 4);
  xt_kernel<<<NTOK / 4, 256, 0, stream>>>(X, W, bias, tgt, xt);
  gemm_lse_kernel<<<NT_M * NT_N, 256, 0, stream>>>(Xb, Wb, bias, pmax, psum);
  lse_kernel<<<NTOK / 4, 256, 0, stream>>>(pmax, psum, xt, tgt, loss);
  final_kernel<<<1, 256, 0, stream>>>(loss, tgt, out);
}

// Round 3
// 860.349 us; speedup vs baseline: 1.0457x; 1.0457x over previous
//
#include <hip/hip_runtime.h>
#include <hip/hip_bf16.h>

#define IGNORE_INDEX (-100)

typedef __bf16 bf16_t;
typedef __bf16 bf16x8 __attribute__((ext_vector_type(8)));
typedef float f32x4 __attribute__((ext_vector_type(4)));

constexpr int NTOK = 4096;
constexpr int HID  = 2048;
constexpr int VOC  = 32000;
constexpr int BM = 256, BN = 256, BK = 32;
constexpr int NT_N = VOC / BN;   // 125 n-tiles
constexpr int NT_M = NTOK / BM;  // 16 m-tiles
constexpr int KT = HID / BK;     // 64 K-tiles

// ---- ws layout (bytes) ----
// Wbf  @ 0          : 32000*2048*2 = 131,072,000
// Xbf  @ 131072000  :  4096*2048*2 =  16,777,216
// pmax @ 147849216  :   125*4096*4 =   2,048,000   ([ntile][row])
// psum @ 149897216  :   125*4096*4 =   2,048,000
// xt   @ 151945216  :      4096*4
// loss @ 151961600  :      4096*4

__device__ __forceinline__ unsigned short f2bf(float f) {
  unsigned int x = __float_as_uint(f);
  return (unsigned short)((x + 0x7fffu + ((x >> 16) & 1u)) >> 16);  // RNE
}

__global__ void cvt_kernel(const float* __restrict__ src, unsigned short* __restrict__ dst, size_t n4) {
  size_t i = (size_t)blockIdx.x * blockDim.x + threadIdx.x;
  size_t stride = (size_t)gridDim.x * blockDim.x;
  const float4* s4 = reinterpret_cast<const float4*>(src);
  ushort4* d4 = reinterpret_cast<ushort4*>(dst);
  for (; i < n4; i += stride) {
    float4 a = s4[i];
    ushort4 o;
    o.x = f2bf(a.x); o.y = f2bf(a.y); o.z = f2bf(a.z); o.w = f2bf(a.w);
    d4[i] = o;
  }
}

// x_t[row] = dot(X[row], W[target[row]]) + bias[target[row]]   (fp32)
__global__ void xt_kernel(const float* __restrict__ X, const float* __restrict__ W,
                          const float* __restrict__ bias, const int* __restrict__ tgt,
                          float* __restrict__ xt) {
  int row = blockIdx.x * 4 + (threadIdx.x >> 6);
  int lane = threadIdx.x & 63;
  if (row >= NTOK) return;
  int t = tgt[row];
  if (t < 0 || t >= VOC) { if (lane == 0) xt[row] = 0.0f; return; }
  const float4* xr = reinterpret_cast<const float4*>(X + (size_t)row * HID);
  const float4* wr = reinterpret_cast<const float4*>(W + (size_t)t * HID);
  float s = 0.0f;
  for (int i = lane; i < HID / 4; i += 64) {
    float4 a = xr[i], b = wr[i];
    s += a.x * b.x + a.y * b.y + a.z * b.z + a.w * b.w;
  }
#pragma unroll
  for (int d = 1; d < 64; d <<= 1) s += __shfl_xor(s, d);
  if (lane == 0) xt[row] = s + bias[t];
}

// Fused bf16 GEMM (logits tile) + per-row (max, sumexp) partials.
// 256x256 tile, BK=32, 8 waves (2M x 4N), 4-buffer LDS ring, depth-3 prefetch,
// counted vmcnt(8) (loads stay in flight across barriers), setprio around MFMA,
// XOR-swizzled LDS chunks (chunk ^= (row>>2)&3), inverse-swizzle on global src.
__global__ __launch_bounds__(512, 2) void gemm_lse_kernel(
    const bf16_t* __restrict__ Xb, const bf16_t* __restrict__ Wb,
    const float* __restrict__ bias,
    float* __restrict__ pmax, float* __restrict__ psum) {
  __shared__ __align__(16) bf16_t sA[4][BM * BK];  // 4 x 16 KB
  __shared__ __align__(16) bf16_t sB[4][BN * BK];  // 4 x 16 KB
  __shared__ float redM[4][BM];
  __shared__ float redS[4][BM];

  // XCD-chunked swizzle, mtile-fastest (2000 % 8 == 0, bijective)
  const int nwg = NT_M * NT_N;           // 2000
  const int xcd = blockIdx.x & 7;
  const int pos = blockIdx.x >> 3;
  const int wgid = xcd * (nwg >> 3) + pos;
  const int mtile = wgid & (NT_M - 1);   // 16 consecutive blocks share W panel
  const int ntile = wgid >> 4;
  const int mbase = mtile * BM;
  const int nbase = ntile * BN;

  const int tid = threadIdx.x;
  const int w = tid >> 6;                // 0..7
  const int lane = tid & 63;
  const int wm = w >> 2, wn = w & 3;     // wave -> 128x64 output sub-tile
  const int l15 = lane & 15;
  const int kgrp = lane >> 4;            // 0..3

  // ---- staging geometry: linear LDS dest, inverse-swizzled global source ----
  // issue (w,i) covers LDS rows (w*2+i)*16 + (lane>>2), stored chunk s = lane&3.
  // stored chunk s at row r holds global chunk c = s ^ ((r>>2)&3); (r>>2)&3 = (lane>>4)&3.
  const int s_row = lane >> 2;                       // 0..15 within issue
  const int c_src = (lane & 3) ^ ((lane >> 4) & 3);  // global chunk for this lane
  const int r0 = w * 32 + s_row;                     // i=0 row
  const bf16_t* aSt0 = Xb + (size_t)(mbase + r0) * HID + c_src * 8;
  const bf16_t* aSt1 = aSt0 + (size_t)16 * HID;      // i=1: +16 rows
  const bf16_t* bSt0 = Wb + (size_t)(nbase + r0) * HID + c_src * 8;
  const bf16_t* bSt1 = bSt0 + (size_t)16 * HID;
  const int sdst = w * 1024;                         // element offset, +512 for i=1

  // ds_read geometry: row r, want global chunk kgrp -> stored chunk kgrp ^ ((r>>2)&3);
  // (r>>2)&3 = l15>>2 for all our rows (wm*128, wn*64, mi*16 are 0 mod 4 after >>2).
  const int arow0 = wm * 128 + l15;
  const int brow0 = wn * 64 + l15;
  const int achk = (kgrp ^ (l15 >> 2)) * 8;          // element offset within row

  f32x4 acc[8][4];
#pragma unroll
  for (int mi = 0; mi < 8; ++mi)
#pragma unroll
    for (int ni = 0; ni < 4; ++ni)
#pragma unroll
      for (int j = 0; j < 4; ++j) acc[mi][ni][j] = 0.0f;

  // bias for this wave's 64 output cols (used in epilogue)
  float bv[4];
#pragma unroll
  for (int ni = 0; ni < 4; ++ni) bv[ni] = bias[nbase + wn * 64 + ni * 16 + l15];

#define STAGE(tk, buf)                                                                   \
  {                                                                                      \
    __builtin_amdgcn_global_load_lds(                                                    \
        (const __attribute__((address_space(1))) void*)(aSt0 + (size_t)(tk) * BK),      \
        (__attribute__((address_space(3))) void*)(&sA[(buf)][sdst]), 16, 0, 0);          \
    __builtin_amdgcn_global_load_lds(                                                    \
        (const __attribute__((address_space(1))) void*)(bSt0 + (size_t)(tk) * BK),      \
        (__attribute__((address_space(3))) void*)(&sB[(buf)][sdst]), 16, 0, 0);          \
    __builtin_amdgcn_global_load_lds(                                                    \
        (const __attribute__((address_space(1))) void*)(aSt1 + (size_t)(tk) * BK),      \
        (__attribute__((address_space(3))) void*)(&sA[(buf)][sdst + 512]), 16, 0, 0);    \
    __builtin_amdgcn_global_load_lds(                                                    \
        (const __attribute__((address_space(1))) void*)(bSt1 + (size_t)(tk) * BK),      \
        (__attribute__((address_space(3))) void*)(&sB[(buf)][sdst + 512]), 16, 0, 0);    \
  }

#define COMPUTE(buf)                                                                     \
  {                                                                                      \
    bf16x8 af[8], bg[4];                                                                 \
    const bf16_t* Ab = &sA[(buf)][0];                                                    \
    const bf16_t* Bb = &sB[(buf)][0];                                                    \
    _Pragma("unroll")                                                                    \
    for (int mi = 0; mi < 8; ++mi)                                                       \
      af[mi] = *reinterpret_cast<const bf16x8*>(Ab + (arow0 + mi * 16) * BK + achk);     \
    _Pragma("unroll")                                                                    \
    for (int ni = 0; ni < 4; ++ni)                                                       \
      bg[ni] = *reinterpret_cast<const bf16x8*>(Bb + (brow0 + ni * 16) * BK + achk);     \
    __builtin_amdgcn_s_setprio(1);                                                       \
    _Pragma("unroll")                                                                    \
    for (int mi = 0; mi < 8; ++mi)                                                       \
      _Pragma("unroll")                                                                  \
      for (int ni = 0; ni < 4; ++ni)                                                     \
        acc[mi][ni] = __builtin_amdgcn_mfma_f32_16x16x32_bf16(af[mi], bg[ni],            \
                                                              acc[mi][ni], 0, 0, 0);     \
    __builtin_amdgcn_s_setprio(0);                                                       \
  }

  // prologue: prefetch tiles 0,1,2 (12 loads); wait tile 0 (drain to 8)
  STAGE(0, 0);
  STAGE(1, 1);
  STAGE(2, 2);
  asm volatile("s_waitcnt vmcnt(8)" ::: "memory");
  __builtin_amdgcn_s_barrier();

  // main loop: tiles 0..KT-4; stage t+3, compute t, wait tile t+1 (counted vmcnt)
  for (int t = 0; t < KT - 3; ++t) {
    STAGE(t + 3, (t + 3) & 3);
    COMPUTE(t & 3);
    asm volatile("s_waitcnt vmcnt(8)" ::: "memory");
    __builtin_amdgcn_s_barrier();
  }
  // tail: tiles KT-3, KT-2, KT-1 (no more staging; drain progressively)
  COMPUTE((KT - 3) & 3);
  asm volatile("s_waitcnt vmcnt(4)" ::: "memory");
  __builtin_amdgcn_s_barrier();
  COMPUTE((KT - 2) & 3);
  asm volatile("s_waitcnt vmcnt(0)" ::: "memory");
  __builtin_amdgcn_s_barrier();
  COMPUTE((KT - 1) & 3);

#undef STAGE
#undef COMPUTE

  // ---- epilogue: per-row (max, sumexp) over this block's 256 cols ----
  // C frag: col = l15, row = kgrp*4 + j (m89-verified, same as passing rounds)
#pragma unroll
  for (int mi = 0; mi < 8; ++mi) {
#pragma unroll
    for (int j = 0; j < 4; ++j) {
      float v0 = acc[mi][0][j] + bv[0];
      float v1 = acc[mi][1][j] + bv[1];
      float v2 = acc[mi][2][j] + bv[2];
      float v3 = acc[mi][3][j] + bv[3];
      float mx = fmaxf(fmaxf(v0, v1), fmaxf(v2, v3));
#pragma unroll
      for (int d = 1; d < 16; d <<= 1) mx = fmaxf(mx, __shfl_xor(mx, d));
      float s = __expf(v0 - mx) + __expf(v1 - mx) + __expf(v2 - mx) + __expf(v3 - mx);
#pragma unroll
      for (int d = 1; d < 16; d <<= 1) s += __shfl_xor(s, d);
      if (l15 == 0) {
        int lr = wm * 128 + mi * 16 + kgrp * 4 + j;
        redM[wn][lr] = mx;
        redS[wn][lr] = s;
      }
    }
  }
  __syncthreads();
  if (tid < BM) {
    float m0 = redM[0][tid], m1 = redM[1][tid], m2 = redM[2][tid], m3 = redM[3][tid];
    float M = fmaxf(fmaxf(m0, m1), fmaxf(m2, m3));
    float S = __expf(m0 - M) * redS[0][tid] + __expf(m1 - M) * redS[1][tid] +
              __expf(m2 - M) * redS[2][tid] + __expf(m3 - M) * redS[3][tid];
    size_t row = (size_t)mbase + tid;
    pmax[(size_t)ntile * NTOK + row] = M;   // coalesced over tid
    psum[(size_t)ntile * NTOK + row] = S;
  }
}

// merge 125 partials per row -> lse -> per-row loss
__global__ void lse_kernel(const float* __restrict__ pmax, const float* __restrict__ psum,
                           const float* __restrict__ xt, const int* __restrict__ tgt,
                           float* __restrict__ loss) {
  int row = blockIdx.x * 4 + (threadIdx.x >> 6);
  int lane = threadIdx.x & 63;
  if (row >= NTOK) return;
  float M = -3.4e38f;
  for (int i = lane; i < NT_N; i += 64) M = fmaxf(M, pmax[(size_t)i * NTOK + row]);
#pragma unroll
  for (int d = 1; d < 64; d <<= 1) M = fmaxf(M, __shfl_xor(M, d));
  float S = 0.0f;
  for (int i = lane; i < NT_N; i += 64)
    S += __expf(pmax[(size_t)i * NTOK + row] - M) * psum[(size_t)i * NTOK + row];
#pragma unroll
  for (int d = 1; d < 64; d <<= 1) S += __shfl_xor(S, d);
  if (lane == 0) {
    int tg = tgt[row];
    bool valid = (tg != IGNORE_INDEX);
    float lse = M + __logf(S);
    loss[row] = valid ? (lse - xt[row]) : 0.0f;
  }
}

__global__ void final_kernel(const float* __restrict__ loss, const int* __restrict__ tgt,
                             float* __restrict__ out) {
  __shared__ float shs[256];
  __shared__ float shc[256];
  int tid = threadIdx.x;
  float s = 0.0f, c = 0.0f;
  for (int i = tid; i < NTOK; i += 256) {
    s += loss[i];
    c += (tgt[i] != IGNORE_INDEX) ? 1.0f : 0.0f;
  }
  shs[tid] = s; shc[tid] = c;
  __syncthreads();
  for (int off = 128; off > 0; off >>= 1) {
    if (tid < off) { shs[tid] += shs[tid + off]; shc[tid] += shc[tid + off]; }
    __syncthreads();
  }
  if (tid == 0) out[0] = shs[0] / fmaxf(shc[0], 1.0f);
}

extern "C" void kernel_launch(void* const* d_in, const int* in_sizes, int n_in,
                              void* d_out, int out_size, void* d_ws, size_t ws_size,
                              hipStream_t stream) {
  const float* W    = (const float*)d_in[0];  // [32000][2048]
  const float* X    = (const float*)d_in[1];  // [4096][2048]
  const int*   tgt  = (const int*)d_in[2];    // [4096]
  const float* bias = (const float*)d_in[3];  // [32000]
  float* out = (float*)d_out;

  char* ws = (char*)d_ws;
  bf16_t* Wb   = (bf16_t*)(ws);
  bf16_t* Xb   = (bf16_t*)(ws + 131072000);
  float*  pmax = (float*) (ws + 147849216);
  float*  psum = (float*) (ws + 149897216);
  float*  xt   = (float*) (ws + 151945216);
  float*  loss = (float*) (ws + 151961600);

  cvt_kernel<<<2048, 256, 0, stream>>>(W, (unsigned short*)Wb, (size_t)VOC * HID / 4);
  cvt_kernel<<<512, 256, 0, stream>>>(X, (unsigned short*)Xb, (size_t)NTOK * HID / 4);
  xt_kernel<<<NTOK / 4, 256, 0, stream>>>(X, W, bias, tgt, xt);
  gemm_lse_kernel<<<NT_M * NT_N, 512, 0, stream>>>(Xb, Wb, bias, pmax, psum);
  lse_kernel<<<NTOK / 4, 256, 0, stream>>>(pmax, psum, xt, tgt, loss);
  final_kernel<<<1, 256, 0, stream>>>(loss, tgt, out);
}

// Round 4
// 817.162 us; speedup vs baseline: 1.1009x; 1.0528x over previous
//
#include <hip/hip_runtime.h>
#include <hip/hip_bf16.h>

#define IGNORE_INDEX (-100)

typedef __bf16 bf16_t;
typedef __bf16 bf16x8 __attribute__((ext_vector_type(8)));
typedef float f32x4 __attribute__((ext_vector_type(4)));

constexpr int NTOK = 4096;
constexpr int HID  = 2048;
constexpr int VOC  = 32000;
constexpr int BM = 256, BN = 256, BK = 32;
constexpr int NT_N = VOC / BN;   // 125 n-tiles
constexpr int NT_M = NTOK / BM;  // 16 m-tiles
constexpr int KT = HID / BK;     // 64 K-tiles

// ---- ws layout (bytes) ----
// Wbf  @ 0          : 32000*2048*2 = 131,072,000
// Xbf  @ 131072000  :  4096*2048*2 =  16,777,216
// pmax @ 147849216  :   125*4096*4 =   2,048,000   ([ntile][row])
// psum @ 149897216  :   125*4096*4 =   2,048,000
// xt   @ 151945216  :      4096*4
// loss @ 151961600  :      4096*4

__device__ __forceinline__ unsigned short f2bf(float f) {
  unsigned int x = __float_as_uint(f);
  return (unsigned short)((x + 0x7fffu + ((x >> 16) & 1u)) >> 16);  // RNE
}

__global__ void cvt_kernel(const float* __restrict__ src, unsigned short* __restrict__ dst, size_t n4) {
  size_t i = (size_t)blockIdx.x * blockDim.x + threadIdx.x;
  size_t stride = (size_t)gridDim.x * blockDim.x;
  const float4* s4 = reinterpret_cast<const float4*>(src);
  ushort4* d4 = reinterpret_cast<ushort4*>(dst);
  for (; i < n4; i += stride) {
    float4 a = s4[i];
    ushort4 o;
    o.x = f2bf(a.x); o.y = f2bf(a.y); o.z = f2bf(a.z); o.w = f2bf(a.w);
    d4[i] = o;
  }
}

// x_t[row] = dot(X[row], W[target[row]]) + bias[target[row]]   (fp32)
__global__ void xt_kernel(const float* __restrict__ X, const float* __restrict__ W,
                          const float* __restrict__ bias, const int* __restrict__ tgt,
                          float* __restrict__ xt) {
  int row = blockIdx.x * 4 + (threadIdx.x >> 6);
  int lane = threadIdx.x & 63;
  if (row >= NTOK) return;
  int t = tgt[row];
  if (t < 0 || t >= VOC) { if (lane == 0) xt[row] = 0.0f; return; }
  const float4* xr = reinterpret_cast<const float4*>(X + (size_t)row * HID);
  const float4* wr = reinterpret_cast<const float4*>(W + (size_t)t * HID);
  float s = 0.0f;
  for (int i = lane; i < HID / 4; i += 64) {
    float4 a = xr[i], b = wr[i];
    s += a.x * b.x + a.y * b.y + a.z * b.z + a.w * b.w;
  }
#pragma unroll
  for (int d = 1; d < 64; d <<= 1) s += __shfl_xor(s, d);
  if (lane == 0) xt[row] = s + bias[t];
}

// Fused bf16 GEMM (logits tile) + per-row (max, sumexp) partials.
// 256x256 tile, BK=32, 8 waves (2M x 4N), 4-buffer LDS ring, stage t+3,
// 2 phases/K-tile {ds_read || stage -> bar -> MFMA(16) -> bar}, counted
// vmcnt(8) once per K-tile (never 0 in main loop), setprio around MFMA.
// Swizzle: stored chunk = c ^ ((row>>1)&3): 8 consecutive rows cover all 8
// 16B bank-slots (zero-conflict pattern, matches R2's measured-0 structure).
__global__ __launch_bounds__(512, 2) void gemm_lse_kernel(
    const bf16_t* __restrict__ Xb, const bf16_t* __restrict__ Wb,
    const float* __restrict__ bias,
    float* __restrict__ pmax, float* __restrict__ psum) {
  __shared__ __align__(16) bf16_t sA[4][BM * BK];  // 4 x 16 KB
  __shared__ __align__(16) bf16_t sB[4][BN * BK];  // 4 x 16 KB
  __shared__ float redM[4][BM];
  __shared__ float redS[4][BM];

  // XCD-chunked swizzle, mtile-fastest (2000 % 8 == 0, bijective)
  const int nwg = NT_M * NT_N;           // 2000
  const int xcd = blockIdx.x & 7;
  const int pos = blockIdx.x >> 3;
  const int wgid = xcd * (nwg >> 3) + pos;
  const int mtile = wgid & (NT_M - 1);   // 16 consecutive blocks share W panel
  const int ntile = wgid >> 4;
  const int mbase = mtile * BM;
  const int nbase = ntile * BN;

  const int tid = threadIdx.x;
  const int w = tid >> 6;                // 0..7
  const int lane = tid & 63;
  const int wm = w >> 2, wn = w & 3;     // wave -> 128x64 output sub-tile
  const int l15 = lane & 15;
  const int kgrp = lane >> 4;            // 0..3

  // ---- staging: linear LDS dest, inverse-swizzled global source ----
  // thread tid, issue j: LDS elems [(j*4096 + tid*8), +8) -> row = j*128+(tid>>2),
  // stored slot s = tid&3. s holds global chunk c = s ^ ((row>>1)&3),
  // (row>>1)&3 = (tid>>3)&3.
  const int srow = tid >> 2;                          // 0..127
  const int csrc = (tid & 3) ^ ((tid >> 3) & 3);      // global chunk for this lane
  const bf16_t* aSt0 = Xb + (size_t)(mbase + srow) * HID + csrc * 8;
  const bf16_t* aSt1 = aSt0 + (size_t)128 * HID;      // j=1: +128 rows
  const bf16_t* bSt0 = Wb + (size_t)(nbase + srow) * HID + csrc * 8;
  const bf16_t* bSt1 = bSt0 + (size_t)128 * HID;
  const int sdst = tid * 8;                           // elems; j=1 adds 4096

  // ds_read: row r, global chunk kgrp stored at kgrp ^ ((r>>1)&3);
  // (r>>1)&3 = (l15>>1)&3 for all our rows (wm*128, wn*64, mi*16 all ≡0 mod 8).
  const int swz = (kgrp ^ ((l15 >> 1) & 3)) * 8;      // element offset in row
  const int arow0 = wm * 128 + l15;
  const int brow0 = wn * 64 + l15;

  f32x4 acc[8][4];
#pragma unroll
  for (int mi = 0; mi < 8; ++mi)
#pragma unroll
    for (int ni = 0; ni < 4; ++ni)
#pragma unroll
      for (int j = 0; j < 4; ++j) acc[mi][ni][j] = 0.0f;

  float bv[4];
#pragma unroll
  for (int ni = 0; ni < 4; ++ni) bv[ni] = bias[nbase + wn * 64 + ni * 16 + l15];

#define GLDS(SRC, DST)                                                              \
  __builtin_amdgcn_global_load_lds((const __attribute__((address_space(1))) void*)(SRC), \
                                   (__attribute__((address_space(3))) void*)(DST), 16, 0, 0)
#define STAGE_A(tk)                                                                 \
  { int b_ = (tk) & 3;                                                              \
    GLDS(aSt0 + (size_t)(tk) * BK, &sA[b_][sdst]);                                  \
    GLDS(aSt1 + (size_t)(tk) * BK, &sA[b_][sdst + 4096]); }
#define STAGE_B(tk)                                                                 \
  { int b_ = (tk) & 3;                                                              \
    GLDS(bSt0 + (size_t)(tk) * BK, &sB[b_][sdst]);                                  \
    GLDS(bSt1 + (size_t)(tk) * BK, &sB[b_][sdst + 4096]); }

  // TILE body: Ph0 {read A0-3,B0-3; stageA; bar; MFMA 16; bar}
  //            Ph1 {read A4-7; stageB; VM; bar; MFMA 16; bar}
#define TILE(T, DO_STAGE, VMASM)                                                    \
  {                                                                                 \
    const bf16_t* Ab = &sA[(T) & 3][0];                                             \
    const bf16_t* Bb = &sB[(T) & 3][0];                                             \
    bf16x8 a0[4], bg[4];                                                            \
    _Pragma("unroll")                                                               \
    for (int mi = 0; mi < 4; ++mi)                                                  \
      a0[mi] = *reinterpret_cast<const bf16x8*>(Ab + (arow0 + mi * 16) * BK + swz); \
    _Pragma("unroll")                                                               \
    for (int ni = 0; ni < 4; ++ni)                                                  \
      bg[ni] = *reinterpret_cast<const bf16x8*>(Bb + (brow0 + ni * 16) * BK + swz); \
    if (DO_STAGE) STAGE_A((T) + 3);                                                 \
    asm volatile("" ::: "memory");                                                  \
    __builtin_amdgcn_s_barrier();                                                   \
    __builtin_amdgcn_s_setprio(1);                                                  \
    _Pragma("unroll")                                                               \
    for (int mi = 0; mi < 4; ++mi)                                                  \
      _Pragma("unroll")                                                             \
      for (int ni = 0; ni < 4; ++ni)                                                \
        acc[mi][ni] = __builtin_amdgcn_mfma_f32_16x16x32_bf16(a0[mi], bg[ni],       \
                                                              acc[mi][ni], 0, 0, 0);\
    __builtin_amdgcn_s_setprio(0);                                                  \
    asm volatile("" ::: "memory");                                                  \
    __builtin_amdgcn_s_barrier();                                                   \
    bf16x8 a1[4];                                                                   \
    _Pragma("unroll")                                                               \
    for (int mi = 0; mi < 4; ++mi)                                                  \
      a1[mi] = *reinterpret_cast<const bf16x8*>(Ab + (arow0 + (mi + 4) * 16) * BK + swz); \
    if (DO_STAGE) STAGE_B((T) + 3);                                                 \
    asm volatile(VMASM ::: "memory");                                               \
    __builtin_amdgcn_s_barrier();                                                   \
    __builtin_amdgcn_s_setprio(1);                                                  \
    _Pragma("unroll")                                                               \
    for (int mi = 0; mi < 4; ++mi)                                                  \
      _Pragma("unroll")                                                             \
      for (int ni = 0; ni < 4; ++ni)                                                \
        acc[mi + 4][ni] = __builtin_amdgcn_mfma_f32_16x16x32_bf16(a1[mi], bg[ni],   \
                                                              acc[mi + 4][ni], 0, 0, 0); \
    __builtin_amdgcn_s_setprio(0);                                                  \
    asm volatile("" ::: "memory");                                                  \
    __builtin_amdgcn_s_barrier();                                                   \
  }

  // prologue: stage tiles 0,1,2 (tile-major: A,B per tile) = 12 loads/thread
  STAGE_A(0); STAGE_B(0);
  STAGE_A(1); STAGE_B(1);
  STAGE_A(2); STAGE_B(2);
  asm volatile("s_waitcnt vmcnt(8)" ::: "memory");   // tile 0 landed
  __builtin_amdgcn_s_barrier();

  // main loop: t = 0..KT-4, stage t+3, vmcnt(8) covers through tile t+1
  for (int t = 0; t < KT - 3; ++t)
    TILE(t, true, "s_waitcnt vmcnt(8)")
  // tail: no more stages; drain progressively (covers t+1 each time)
  TILE(KT - 3, false, "s_waitcnt vmcnt(4)")
  TILE(KT - 2, false, "s_waitcnt vmcnt(0)")
  TILE(KT - 1, false, "")

#undef TILE
#undef STAGE_A
#undef STAGE_B
#undef GLDS

  // ---- epilogue: per-row (max, sumexp) over this block's 256 cols ----
  // C frag: col = l15, row = kgrp*4 + j (m89-verified)
#pragma unroll
  for (int mi = 0; mi < 8; ++mi) {
#pragma unroll
    for (int j = 0; j < 4; ++j) {
      float v0 = acc[mi][0][j] + bv[0];
      float v1 = acc[mi][1][j] + bv[1];
      float v2 = acc[mi][2][j] + bv[2];
      float v3 = acc[mi][3][j] + bv[3];
      float mx = fmaxf(fmaxf(v0, v1), fmaxf(v2, v3));
#pragma unroll
      for (int d = 1; d < 16; d <<= 1) mx = fmaxf(mx, __shfl_xor(mx, d));
      float s = __expf(v0 - mx) + __expf(v1 - mx) + __expf(v2 - mx) + __expf(v3 - mx);
#pragma unroll
      for (int d = 1; d < 16; d <<= 1) s += __shfl_xor(s, d);
      if (l15 == 0) {
        int lr = wm * 128 + mi * 16 + kgrp * 4 + j;
        redM[wn][lr] = mx;
        redS[wn][lr] = s;
      }
    }
  }
  __syncthreads();
  if (tid < BM) {
    float m0 = redM[0][tid], m1 = redM[1][tid], m2 = redM[2][tid], m3 = redM[3][tid];
    float M = fmaxf(fmaxf(m0, m1), fmaxf(m2, m3));
    float S = __expf(m0 - M) * redS[0][tid] + __expf(m1 - M) * redS[1][tid] +
              __expf(m2 - M) * redS[2][tid] + __expf(m3 - M) * redS[3][tid];
    size_t row = (size_t)mbase + tid;
    pmax[(size_t)ntile * NTOK + row] = M;   // coalesced over tid
    psum[(size_t)ntile * NTOK + row] = S;
  }
}

// merge 125 partials per row -> lse -> per-row loss
__global__ void lse_kernel(const float* __restrict__ pmax, const float* __restrict__ psum,
                           const float* __restrict__ xt, const int* __restrict__ tgt,
                           float* __restrict__ loss) {
  int row = blockIdx.x * 4 + (threadIdx.x >> 6);
  int lane = threadIdx.x & 63;
  if (row >= NTOK) return;
  float M = -3.4e38f;
  for (int i = lane; i < NT_N; i += 64) M = fmaxf(M, pmax[(size_t)i * NTOK + row]);
#pragma unroll
  for (int d = 1; d < 64; d <<= 1) M = fmaxf(M, __shfl_xor(M, d));
  float S = 0.0f;
  for (int i = lane; i < NT_N; i += 64)
    S += __expf(pmax[(size_t)i * NTOK + row] - M) * psum[(size_t)i * NTOK + row];
#pragma unroll
  for (int d = 1; d < 64; d <<= 1) S += __shfl_xor(S, d);
  if (lane == 0) {
    int tg = tgt[row];
    bool valid = (tg != IGNORE_INDEX);
    float lse = M + __logf(S);
    loss[row] = valid ? (lse - xt[row]) : 0.0f;
  }
}

__global__ void final_kernel(const float* __restrict__ loss, const int* __restrict__ tgt,
                             float* __restrict__ out) {
  __shared__ float shs[256];
  __shared__ float shc[256];
  int tid = threadIdx.x;
  float s = 0.0f, c = 0.0f;
  for (int i = tid; i < NTOK; i += 256) {
    s += loss[i];
    c += (tgt[i] != IGNORE_INDEX) ? 1.0f : 0.0f;
  }
  shs[tid] = s; shc[tid] = c;
  __syncthreads();
  for (int off = 128; off > 0; off >>= 1) {
    if (tid < off) { shs[tid] += shs[tid + off]; shc[tid] += shc[tid + off]; }
    __syncthreads();
  }
  if (tid == 0) out[0] = shs[0] / fmaxf(shc[0], 1.0f);
}

extern "C" void kernel_launch(void* const* d_in, const int* in_sizes, int n_in,
                              void* d_out, int out_size, void* d_ws, size_t ws_size,
                              hipStream_t stream) {
  const float* W    = (const float*)d_in[0];  // [32000][2048]
  const float* X    = (const float*)d_in[1];  // [4096][2048]
  const int*   tgt  = (const int*)d_in[2];    // [4096]
  const float* bias = (const float*)d_in[3];  // [32000]
  float* out = (float*)d_out;

  char* ws = (char*)d_ws;
  bf16_t* Wb   = (bf16_t*)(ws);
  bf16_t* Xb   = (bf16_t*)(ws + 131072000);
  float*  pmax = (float*) (ws + 147849216);
  float*  psum = (float*) (ws + 149897216);
  float*  xt   = (float*) (ws + 151945216);
  float*  loss = (float*) (ws + 151961600);

  cvt_kernel<<<2048, 256, 0, stream>>>(W, (unsigned short*)Wb, (size_t)VOC * HID / 4);
  cvt_kernel<<<512, 256, 0, stream>>>(X, (unsigned short*)Xb, (size_t)NTOK * HID / 4);
  xt_kernel<<<NTOK / 4, 256, 0, stream>>>(X, W, bias, tgt, xt);
  gemm_lse_kernel<<<NT_M * NT_N, 512, 0, stream>>>(Xb, Wb, bias, pmax, psum);
  lse_kernel<<<NTOK / 4, 256, 0, stream>>>(pmax, psum, xt, tgt, loss);
  final_kernel<<<1, 256, 0, stream>>>(loss, tgt, out);
}